// Round 6
// baseline (2470.679 us; speedup 1.0000x reference)
//
#include <hip/hip_runtime.h>
#include <math.h>

// Problem constants (EnhancedVectorQuantizer): inputs (16,4096,256) f32, emb (2048,256) f32
#define NROWS  65536
#define DIM    256
#define KCODES 2048

#define Q_OFF  16777216   // NROWS*DIM; d_out layout: [0,Q_OFF) quantized_st, [Q_OFF]=loss, [Q_OFF+1]=perplexity, [Q_OFF+2..) idx as f32

// workspace byte offsets
#define WS_C      0        // 2048 f32  ||e_k||^2
#define WS_INV    8192     // 2048 f32  1/max(rownorm,1e-12)
#define WS_COUNTS 16384    // 2048 u32
#define WS_SUMS   24576    // 3 doubles: [0]=mse_sum [1]=l2_sum [2]=orth_sum
#define WS_IDX    32768    // 65536 i32

typedef __attribute__((address_space(1))) const void gvoid_t;
typedef __attribute__((address_space(3))) void lvoid_t;

// ---------------- init: zero accumulators (ws is poisoned 0xAA every launch) ----------------
__global__ void vq_init_kernel(unsigned* __restrict__ counts, double* __restrict__ sums) {
    int t = threadIdx.x;
    for (int k = t; k < KCODES; k += 256) counts[k] = 0u;
    if (t < 3) sums[t] = 0.0;
}

// ---------------- prep: c[k]=||e_k||^2, inv rownorm, l2 sum ----------------
__global__ void vq_prep_kernel(const float* __restrict__ emb, float* __restrict__ c,
                               float* __restrict__ invn, double* __restrict__ sums) {
    int k = blockIdx.x;
    int lane = threadIdx.x;                       // 64 lanes
    float4 v = ((const float4*)(emb + (size_t)k * DIM))[lane];
    float s = v.x * v.x + v.y * v.y + v.z * v.z + v.w * v.w;
    #pragma unroll
    for (int off = 32; off > 0; off >>= 1) s += __shfl_down(s, off, 64);
    if (lane == 0) {
        c[k] = s;
        float rn = sqrtf(s);
        invn[k] = 1.0f / fmaxf(rn, 1e-12f);
        atomicAdd(&sums[1], (double)rn);
    }
}

// ---------------- argmin: async-DMA double-buffered fp32 distance GEMM + argmin ----------------
// 256 threads (tx=tid&15 codes {tx+16i}, ty=tid>>4 rows {ty+16j}).
// BM=64 rows/block, BN=64 codes, BK=64 dims/chunk; 128 steps = 32 kt x 4 dk.
//
// Round-5 failure: first launch exact (absmax 0.0) but graph replays intermittently
// produced wrong idx -> timing race. Root cause hypothesis: the compiler's implicit
// "s_waitcnt vmcnt(0) before s_barrier" (which the whole double-buffer ordering
// depends on for the LDS-DMA writes) was not emitted for the conditional DMA block —
// LLVM's LDS-DMA vmcnt tracking is the one unverifiable link. Compute phase (~2240cyc)
// vs DMA (~900cyc) means the race is marginal: passes once, fails in ~100 replays.
// Fix: EXPLICIT __builtin_amdgcn_s_waitcnt(0) (vmcnt=0,lgkmcnt=0) before every
// __syncthreads(), making the ordering source-guaranteed:
//   at each barrier, every wave's DMAs for s+1 have landed and its reads of buf[s&1]
//   are done; the barrier globalizes both -> step s+1 reads are safe, and the DMA
//   target buf[s&1] at step s+1 has no pending readers.
//
// DMA writes wave-uniform base + lane*16 (no padding possible), so bank conflicts are
// broken with a XOR swizzle: 16B chunk c of row r stored at slot c ^ (r&7).
// Storage-only permutation: dd-ascending accumulation order is bit-identical to the
// reference-validated chain (rounds 1/3/4, absmax 0.0).
#define BM 64
#define BN 64
#define BK 64

__global__ __launch_bounds__(256)
__attribute__((amdgpu_waves_per_eu(2, 2)))
void vq_argmin_kernel(const float* __restrict__ x, const float* __restrict__ emb,
                      const float* __restrict__ c, int* __restrict__ idx_ws,
                      float* __restrict__ idx_f, unsigned* __restrict__ counts) {
    __shared__ float As[2][4096];   // [buf][64 rows x 64 floats], 16 segs of 1KB, xor-swizzled
    __shared__ float Bs[2][4096];
    __shared__ float x2s[BM];

    const int tid  = threadIdx.x;
    const int tx   = tid & 15, ty = tid >> 4;
    const int wave = tid >> 6, lane = tid & 63;
    const int row0 = blockIdx.x * BM;

    const float4* x4 = (const float4*)x;
    const float4* e4 = (const float4*)emb;

    // per-row ||x||^2 — float4 loads, serial component adds: identical rounding
    // chain to the scalar loop that matched the reference exactly.
    if (tid < BM) {
        const float4* xr = (const float4*)(x + (size_t)(row0 + tid) * DIM);
        float s = 0.f;
        for (int d4 = 0; d4 < DIM / 4; ++d4) {
            float4 v = xr[d4];
            s += v.x * v.x; s += v.y * v.y; s += v.z * v.z; s += v.w * v.w;
        }
        x2s[tid] = s;
    }

    const int rsub = lane >> 4;      // row within 4-row segment
    const int cp   = lane & 15;      // LDS chunk slot

    // ---- stage step 0 (kt=0, dk=0) into buf 0 ----
    #pragma unroll
    for (int q = 0; q < 4; ++q) {
        int s  = wave + 4 * q;               // segment 0..15
        int ra = 4 * s + rsub;               // row in tile
        int ca = cp ^ (ra & 7);              // logical chunk for this slot
        __builtin_amdgcn_global_load_lds((gvoid_t*)(x4 + ((size_t)(row0 + ra) * 64 + ca)),
                                         (lvoid_t*)(&As[0][s * 256]), 16, 0, 0);
        __builtin_amdgcn_global_load_lds((gvoid_t*)(e4 + ((size_t)ra * 64 + ca)),
                                         (lvoid_t*)(&Bs[0][s * 256]), 16, 0, 0);
    }
    __builtin_amdgcn_s_waitcnt(0);           // explicit vmcnt(0)+lgkmcnt(0): DMA landed
    __syncthreads();

    float x2r[4];
    #pragma unroll
    for (int j = 0; j < 4; ++j) x2r[j] = x2s[ty + 16 * j];

    // per-frag byte offsets into As/Bs pair; bit14 toggles the buffer
    int aoff[4], boff[4];
    #pragma unroll
    for (int j = 0; j < 4; ++j) {
        int r = ty + 16 * j;
        aoff[j] = (((r >> 2) << 10) + ((r & 3) << 8)) ^ ((r & 7) << 4);
    }
    #pragma unroll
    for (int i = 0; i < 4; ++i) {
        int r = tx + 16 * i;
        boff[i] = (((r >> 2) << 10) + ((r & 3) << 8)) ^ ((r & 7) << 4);
    }

    float best[4]; int bidx[4];
    #pragma unroll
    for (int j = 0; j < 4; ++j) { best[j] = 3.4e38f; bidx[j] = 0; }

    float acc[4][4];
    #pragma unroll
    for (int j = 0; j < 4; ++j)
        #pragma unroll
        for (int i = 0; i < 4; ++i) acc[j][i] = 0.f;

    const char* AsB = (const char*)&As[0][0];
    const char* BsB = (const char*)&Bs[0][0];

    for (int s = 0; s < 128; ++s) {
        // issue async DMA for step s+1 into buf[(s+1)&1] (that buffer's last readers
        // finished at step s-1, behind the previous barrier's full drain)
        if (s < 127) {
            int sn   = s + 1;
            int dk4  = (sn & 3) << 4;        // float4 column offset
            int ktn  = (sn >> 2) << 6;       // code-tile base row
            float* Ad = &As[sn & 1][0];
            float* Bd = &Bs[sn & 1][0];
            #pragma unroll
            for (int q = 0; q < 4; ++q) {
                int sg = wave + 4 * q;
                int ra = 4 * sg + rsub;
                int ca = cp ^ (ra & 7);
                __builtin_amdgcn_global_load_lds((gvoid_t*)(x4 + ((size_t)(row0 + ra) * 64 + dk4 + ca)),
                                                 (lvoid_t*)(Ad + sg * 256), 16, 0, 0);
                __builtin_amdgcn_global_load_lds((gvoid_t*)(e4 + ((size_t)(ktn + ra) * 64 + dk4 + ca)),
                                                 (lvoid_t*)(Bd + sg * 256), 16, 0, 0);
            }
        }

        // compute from buf[s&1]: acc[j][i] += x_row(j) . e_code(i), ascending dd
        #pragma unroll
        for (int dd = 0; dd < BK; dd += 4) {
            float4 a[4], b[4];
            #pragma unroll
            for (int j = 0; j < 4; ++j) a[j] = *(const float4*)(AsB + (aoff[j] ^ (dd << 2)));
            #pragma unroll
            for (int i = 0; i < 4; ++i) b[i] = *(const float4*)(BsB + (boff[i] ^ (dd << 2)));
            #pragma unroll
            for (int j = 0; j < 4; ++j)
                #pragma unroll
                for (int i = 0; i < 4; ++i)
                    acc[j][i] += a[j].x * b[i].x + a[j].y * b[i].y
                               + a[j].z * b[i].z + a[j].w * b[i].w;
        }

        if ((s & 3) == 3) {                  // full D done for this kt tile: fold argmin
            int kt = (s >> 2) << 6;
            #pragma unroll
            for (int i = 0; i < 4; ++i) {
                int k = kt + tx + 16 * i;    // ascending in i -> lowest-index tie win
                float ck = c[k];
                #pragma unroll
                for (int j = 0; j < 4; ++j) {
                    float t = x2r[j] + ck;               // matches reference eval order
                    float dst = t - 2.0f * acc[j][i];    // *2 exact
                    if (dst < best[j]) { best[j] = dst; bidx[j] = k; }
                }
            }
            #pragma unroll
            for (int j = 0; j < 4; ++j)
                #pragma unroll
                for (int i = 0; i < 4; ++i) acc[j][i] = 0.f;
        }

        // toggle buffer bit for fragment addresses
        #pragma unroll
        for (int j = 0; j < 4; ++j) aoff[j] ^= 16384;
        #pragma unroll
        for (int i = 0; i < 4; ++i) boff[i] ^= 16384;

        __builtin_amdgcn_s_waitcnt(0);       // explicit drain: this wave's DMAs for s+1
                                             // landed in LDS, its reads of buf[s&1] done
        __syncthreads();                     // globalize across the block
    }

    // final reduction: reuse As/Bs as redv/redi (behind the loop's last barrier)
    float* redv = &As[0][0];                 // [64][16]
    int*   redi = (int*)&Bs[0][0];
    #pragma unroll
    for (int j = 0; j < 4; ++j) {
        int r = ty + 16 * j;
        redv[r * 16 + tx] = best[j];
        redi[r * 16 + tx] = bidx[j];
    }
    __builtin_amdgcn_s_waitcnt(0);
    __syncthreads();
    if (tid < BM) {
        float bv = redv[tid * 16]; int bi = redi[tid * 16];
        for (int t = 1; t < 16; ++t) {
            float v = redv[tid * 16 + t]; int ii = redi[tid * 16 + t];
            if (v < bv || (v == bv && ii < bi)) { bv = v; bi = ii; }  // ties -> lowest index
        }
        int n = row0 + tid;
        idx_ws[n] = bi;
        idx_f[n] = (float)bi;
        atomicAdd(&counts[bi], 1u);
    }
}

// ---------------- gather: quantized_st = x + (e - x) (matches ST rounding), MSE sum ----------------
__global__ void vq_gather_kernel(const float* __restrict__ x, const float* __restrict__ emb,
                                 const int* __restrict__ idx, float* __restrict__ outq,
                                 double* __restrict__ sums) {
    __shared__ float red[256];
    int tid = threadIdx.x;
    int q = blockIdx.x * 256 + tid;        // float4 index, 4194304 total
    int n = q >> 6;
    int d4 = (q & 63) << 2;
    int k = idx[n];
    float4 e  = *(const float4*)(emb + (size_t)k * DIM + d4);
    float4 xv = *(const float4*)(x + ((size_t)n * DIM + d4));
    float d0 = e.x - xv.x, d1 = e.y - xv.y, d2 = e.z - xv.z, d3 = e.w - xv.w;
    float4 o;
    o.x = xv.x + d0; o.y = xv.y + d1; o.z = xv.z + d2; o.w = xv.w + d3;
    *(float4*)(outq + (size_t)q * 4) = o;
    red[tid] = d0 * d0 + d1 * d1 + d2 * d2 + d3 * d3;
    __syncthreads();
    for (int off = 128; off > 0; off >>= 1) {
        if (tid < off) red[tid] += red[tid + off];
        __syncthreads();
    }
    if (tid == 0) atomicAdd(&sums[0], (double)red[0]);
}

// ---------------- sim: sum |off-diagonal cosine| ----------------
#define SPAD 68
__global__ __launch_bounds__(256)
void vq_sim_kernel(const float* __restrict__ emb, const float* __restrict__ invn,
                   double* __restrict__ sums) {
    __shared__ float Ai[64][SPAD];
    __shared__ float Bj[64][SPAD];
    int bi = blockIdx.x >> 5;
    int bj = blockIdx.x & 31;
    int tid = threadIdx.x;
    int tx = tid & 15, ty = tid >> 4;

    float acc[4][4];
    #pragma unroll
    for (int j = 0; j < 4; ++j)
        #pragma unroll
        for (int i = 0; i < 4; ++i) acc[j][i] = 0.f;

    for (int dc = 0; dc < DIM; dc += 64) {
        #pragma unroll
        for (int rr = 0; rr < 4; ++rr) {
            int row = rr * 16 + ty;
            int col = tx * 4;
            int ga = bi * 64 + row, gb = bj * 64 + row;
            float4 a = *(const float4*)(emb + (size_t)ga * DIM + dc + col);
            float4 b = *(const float4*)(emb + (size_t)gb * DIM + dc + col);
            float sa = invn[ga], sb = invn[gb];
            Ai[row][col + 0] = a.x * sa; Ai[row][col + 1] = a.y * sa;
            Ai[row][col + 2] = a.z * sa; Ai[row][col + 3] = a.w * sa;
            Bj[row][col + 0] = b.x * sb; Bj[row][col + 1] = b.y * sb;
            Bj[row][col + 2] = b.z * sb; Bj[row][col + 3] = b.w * sb;
        }
        __syncthreads();
        for (int d = 0; d < 64; d += 4) {
            float4 a[4], b[4];
            #pragma unroll
            for (int j = 0; j < 4; ++j) a[j] = *(const float4*)&Ai[ty * 4 + j][d];
            #pragma unroll
            for (int i = 0; i < 4; ++i) b[i] = *(const float4*)&Bj[tx * 4 + i][d];
            #pragma unroll
            for (int j = 0; j < 4; ++j)
                #pragma unroll
                for (int i = 0; i < 4; ++i)
                    acc[j][i] += a[j].x * b[i].x + a[j].y * b[i].y
                               + a[j].z * b[i].z + a[j].w * b[i].w;
        }
        __syncthreads();
    }
    float s = 0.f;
    #pragma unroll
    for (int j = 0; j < 4; ++j)
        #pragma unroll
        for (int i = 0; i < 4; ++i) {
            int gi = bi * 64 + ty * 4 + j;
            int gj = bj * 64 + tx * 4 + i;
            if (gi != gj) s += fabsf(acc[j][i]);
        }
    float* red = &Ai[0][0];
    red[tid] = s;
    __syncthreads();
    for (int off = 128; off > 0; off >>= 1) {
        if (tid < off) red[tid] += red[tid + off];
        __syncthreads();
    }
    if (tid == 0) atomicAdd(&sums[2], (double)red[0]);
}

// ---------------- finalize: KL, perplexity, total loss ----------------
__global__ void vq_finalize_kernel(const unsigned* __restrict__ counts,
                                   const double* __restrict__ sums,
                                   float* __restrict__ out_scalars) {
    __shared__ double sred[256];
    int tid = threadIdx.x;
    double t = 0.0;
    for (int k = tid; k < KCODES; k += 256) t += (double)counts[k];
    sred[tid] = t; __syncthreads();
    for (int off = 128; off > 0; off >>= 1) {
        if (tid < off) sred[tid] += sred[tid + off];
        __syncthreads();
    }
    double total = sred[0];
    __syncthreads();

    const double eps = 1e-8, tunif = 1.0 / (double)KCODES;
    double klsum = 0.0, plogpsum = 0.0;
    for (int k = tid; k < KCODES; k += 256) {
        double p = (double)counts[k] / total;
        klsum += (p + eps) * log((p + eps) / (tunif + eps));
        if (p > 0.0) plogpsum += p * log(p);
    }
    sred[tid] = klsum; __syncthreads();
    for (int off = 128; off > 0; off >>= 1) {
        if (tid < off) sred[tid] += sred[tid + off];
        __syncthreads();
    }
    klsum = sred[0];
    __syncthreads();
    sred[tid] = plogpsum; __syncthreads();
    for (int off = 128; off > 0; off >>= 1) {
        if (tid < off) sred[tid] += sred[tid + off];
        __syncthreads();
    }
    plogpsum = sred[0];

    if (tid == 0) {
        float mse = (float)(sums[0] / (double)((size_t)NROWS * DIM));
        float vq = mse + 0.25f * mse;                       // q_latent + COST*e_latent (equal in value)
        float kl = fminf((float)klsum, 100.0f);
        float l2 = fminf((float)(sums[1] / (double)KCODES), 10.0f);
        float orth = fminf((float)(sums[2] / ((double)KCODES * (double)KCODES)), 10.0f);
        float reg = l2 + orth;
        float total_loss = fminf(vq + 0.1f * kl + 0.01f * reg, 100.0f);
        out_scalars[0] = total_loss;
        out_scalars[1] = (float)exp(-plogpsum);
    }
}

extern "C" void kernel_launch(void* const* d_in, const int* in_sizes, int n_in,
                              void* d_out, int out_size, void* d_ws, size_t ws_size,
                              hipStream_t stream) {
    const float* x   = (const float*)d_in[0];   // (16,4096,256) f32
    const float* emb = (const float*)d_in[1];   // (2048,256)   f32
    float* out = (float*)d_out;

    char* ws = (char*)d_ws;
    float*    c      = (float*)(ws + WS_C);
    float*    invn   = (float*)(ws + WS_INV);
    unsigned* counts = (unsigned*)(ws + WS_COUNTS);
    double*   sums   = (double*)(ws + WS_SUMS);
    int*      idx_ws = (int*)(ws + WS_IDX);

    float* outq        = out;                 // quantized_st
    float* out_scalars = out + Q_OFF;         // loss, perplexity
    float* idx_f       = out + Q_OFF + 2;     // idx as float

    vq_init_kernel<<<1, 256, 0, stream>>>(counts, sums);
    vq_prep_kernel<<<KCODES, 64, 0, stream>>>(emb, c, invn, sums);
    vq_argmin_kernel<<<NROWS / BM, 256, 0, stream>>>(x, emb, c, idx_ws, idx_f, counts);
    vq_gather_kernel<<<(NROWS * DIM / 4) / 256, 256, 0, stream>>>(x, emb, idx_ws, outq, sums);
    vq_sim_kernel<<<(KCODES / 64) * (KCODES / 64), 256, 0, stream>>>(emb, invn, sums);
    vq_finalize_kernel<<<1, 256, 0, stream>>>(counts, sums, out_scalars);
}

// Round 7
// 1802.678 us; speedup vs baseline: 1.3706x; 1.3706x over previous
//
#include <hip/hip_runtime.h>
#include <math.h>

// Problem constants (EnhancedVectorQuantizer): inputs (16,4096,256) f32, emb (2048,256) f32
#define NROWS  65536
#define DIM    256
#define KCODES 2048

#define Q_OFF  16777216   // NROWS*DIM; d_out layout: [0,Q_OFF) quantized_st, [Q_OFF]=loss, [Q_OFF+1]=perplexity, [Q_OFF+2..) idx as f32

// workspace byte offsets (total 294912 B)
#define WS_C      0        // 2048 f32  ||e_k||^2
#define WS_INV    8192     // 2048 f32  1/max(rownorm,1e-12)
#define WS_COUNTS 16384    // 2048 u32
#define WS_SUMS   24576    // 3 doubles: [0]=mse_sum [1]=l2_sum [2]=orth_sum
#define WS_X2     32768    // 65536 f32 ||x_n||^2 (replaces idx_ws; gather reads idx from out)

typedef __attribute__((address_space(1))) const void gvoid_t;
typedef __attribute__((address_space(3))) void lvoid_t;

// ---------------- init: zero accumulators (ws is poisoned 0xAA every launch) ----------------
__global__ void vq_init_kernel(unsigned* __restrict__ counts, double* __restrict__ sums) {
    int t = threadIdx.x;
    for (int k = t; k < KCODES; k += 256) counts[k] = 0u;
    if (t < 3) sums[t] = 0.0;
}

// ---------------- prep: c[k]=||e_k||^2, inv rownorm, l2 sum ----------------
__global__ void vq_prep_kernel(const float* __restrict__ emb, float* __restrict__ c,
                               float* __restrict__ invn, double* __restrict__ sums) {
    int k = blockIdx.x;
    int lane = threadIdx.x;                       // 64 lanes
    float4 v = ((const float4*)(emb + (size_t)k * DIM))[lane];
    float s = v.x * v.x + v.y * v.y + v.z * v.z + v.w * v.w;
    #pragma unroll
    for (int off = 32; off > 0; off >>= 1) s += __shfl_down(s, off, 64);
    if (lane == 0) {
        c[k] = s;
        float rn = sqrtf(s);
        invn[k] = 1.0f / fmaxf(rn, 1e-12f);
        atomicAdd(&sums[1], (double)rn);
    }
}

// ---------------- x2: per-row ||x||^2, serial float4 chain (bit-identical to ref order) ----------------
__global__ void vq_x2_kernel(const float* __restrict__ x, float* __restrict__ x2g) {
    int row = blockIdx.x * 256 + threadIdx.x;
    const float4* xr = (const float4*)(x + (size_t)row * DIM);
    float s = 0.f;
    for (int d4 = 0; d4 < DIM / 4; ++d4) {
        float4 v = xr[d4];
        s += v.x * v.x; s += v.y * v.y; s += v.z * v.z; s += v.w * v.w;
    }
    x2g[row] = s;
}

// ---------------- argmin: A-resident LDS + streamed-B fp32 distance GEMM + argmin ----------------
// 256 threads (tx=tid&15 codes {tx+16i}, ty=tid>>4 rows {ty+16j}). BM=64 rows/block.
//
// Round-6 lesson: re-staging A every step cost 2 GB of L2-thrash fetch + the allocator
// scratched 1.4 GB regardless of structure; DMA LDS-writes dominated bank conflicts.
// Fix: A (64 rows x 256 = 64 KB) is loop-invariant -> DMA it ONCE (xor-swizzled);
// stream only B in 8 KB chunks (64 codes x 32 dims), double-buffered. 256 steps =
// 32 kt-tiles x 8 dim-chunks. LDS = 64K + 16K = 80 KB dynamic -> 2 blocks/CU,
// 2 waves/EU (waves_per_eu(2,2) matches). Register demand ~80 < 128: nothing to spill.
// Explicit s_waitcnt(0) before each barrier (round-6 race fix, proven).
//
// Swizzle (storage-only; dim-ascending accumulation chain bit-identical to ref):
//   A: 4 dk-blocks of [16 segs][4 rows][16 chunks], chunk slot = c ^ (r&7)
//      frag read: 4 distinct rows/wave -> 4 distinct bank-quads -> conflict-free
//   B: [8 segs][8 rows][8 chunks], slot = c ^ (r&7)
//      frag read: 16 rows/wave -> 8 quads x 2-way -> free (m136)
#define BM 64

__global__ __launch_bounds__(256)
__attribute__((amdgpu_waves_per_eu(2, 2)))
void vq_argmin_kernel(const float* __restrict__ x, const float* __restrict__ emb,
                      const float* __restrict__ c, const float* __restrict__ x2g,
                      float* __restrict__ idx_f, unsigned* __restrict__ counts) {
    extern __shared__ float smem[];          // 81920 B
    float* Asl = smem;                       // 16384 floats (64 KB)
    float* Bsl = smem + 16384;               // 4096 floats (2 bufs x 8 KB)

    const int tid  = threadIdx.x;
    const int tx   = tid & 15, ty = tid >> 4;
    const int wave = tid >> 6, lane = tid & 63;
    const int row0 = blockIdx.x * BM;

    const float4* x4 = (const float4*)x;
    const float4* e4 = (const float4*)emb;

    // ---- A DMA (once): 4 dk-blocks x 4 segs per wave ----
    {
        int rsub = lane >> 4, cp = lane & 15;
        #pragma unroll
        for (int dk = 0; dk < 4; ++dk)
            #pragma unroll
            for (int q = 0; q < 4; ++q) {
                int sg = wave + 4 * q;           // segment 0..15
                int ra = 4 * sg + rsub;          // row in tile
                int ca = cp ^ (ra & 7);          // logical chunk at this slot
                __builtin_amdgcn_global_load_lds(
                    (gvoid_t*)(x4 + ((size_t)(row0 + ra) * 64 + dk * 16 + ca)),
                    (lvoid_t*)(Asl + dk * 4096 + sg * 256), 16, 0, 0);
            }
    }
    // ---- B DMA step 0 (kt=0, dims [0,32)) ----
    {
        int rsub8 = lane >> 3, cp8 = lane & 7;
        #pragma unroll
        for (int q = 0; q < 2; ++q) {
            int sg = wave + 4 * q;               // segment 0..7
            int rb = 8 * sg + rsub8;
            int cb = cp8 ^ rsub8;                // rb&7 == rsub8
            __builtin_amdgcn_global_load_lds(
                (gvoid_t*)(e4 + ((size_t)rb * 64 + cb)),
                (lvoid_t*)(Bsl + sg * 256), 16, 0, 0);
        }
    }

    // per-row ||x||^2 from precomputed global (same values as inline chain)
    float x2r[4];
    #pragma unroll
    for (int j = 0; j < 4; ++j) x2r[j] = x2g[row0 + ty + 16 * j];

    __builtin_amdgcn_s_waitcnt(0);           // DMA landed in LDS
    __syncthreads();

    // fragment byte offsets (xor field in bits 4-6)
    int aoff[4], boff[4];
    #pragma unroll
    for (int j = 0; j < 4; ++j) {
        int r = ty + 16 * j;
        aoff[j] = ((r >> 2) << 10) + ((r & 3) << 8) + ((r & 7) << 4);
    }
    #pragma unroll
    for (int i = 0; i < 4; ++i) {
        int r = tx + 16 * i;
        boff[i] = ((r >> 3) << 10) + ((r & 7) << 7) + ((r & 7) << 4);
    }

    float best[4]; int bidx[4];
    #pragma unroll
    for (int j = 0; j < 4; ++j) { best[j] = 3.4e38f; bidx[j] = 0; }

    float acc[4][4];
    #pragma unroll
    for (int j = 0; j < 4; ++j)
        #pragma unroll
        for (int i = 0; i < 4; ++i) acc[j][i] = 0.f;

    const char* AsB = (const char*)Asl;
    const char* BsB = (const char*)Bsl;

    for (int s = 0; s < 256; ++s) {
        // async DMA of next B chunk into the other buffer
        if (s < 255) {
            int sn  = s + 1;
            int dk8 = sn & 7;                    // 32-dim chunk index
            int ktn = (sn >> 3) << 6;            // code-tile base row
            float* Bd = Bsl + (sn & 1) * 2048;
            int rsub8 = lane >> 3, cp8 = lane & 7;
            #pragma unroll
            for (int q = 0; q < 2; ++q) {
                int sg = wave + 4 * q;
                int rb = 8 * sg + rsub8;
                int cb = cp8 ^ rsub8;
                __builtin_amdgcn_global_load_lds(
                    (gvoid_t*)(e4 + ((size_t)(ktn + rb) * 64 + dk8 * 8 + cb)),
                    (lvoid_t*)(Bd + sg * 256), 16, 0, 0);
            }
        }

        // compute over this 32-dim chunk; dims ascending -> ref-identical chain
        int dk8c = s & 7;
        int sA = ((dk8c >> 1) << 14) + ((dk8c & 1) << 7);   // A dk-block base bits
        #pragma unroll
        for (int dd = 0; dd < 32; dd += 4) {
            float4 a[4], b[4];
            #pragma unroll
            for (int j = 0; j < 4; ++j) a[j] = *(const float4*)(AsB + ((sA + aoff[j]) ^ (dd << 2)));
            #pragma unroll
            for (int i = 0; i < 4; ++i) b[i] = *(const float4*)(BsB + (boff[i] ^ (dd << 2)));
            #pragma unroll
            for (int j = 0; j < 4; ++j)
                #pragma unroll
                for (int i = 0; i < 4; ++i)
                    acc[j][i] += a[j].x * b[i].x + a[j].y * b[i].y
                               + a[j].z * b[i].z + a[j].w * b[i].w;
        }

        if ((s & 7) == 7) {                      // full D done for this kt tile: fold argmin
            int kt = (s >> 3) << 6;
            #pragma unroll
            for (int i = 0; i < 4; ++i) {
                int k = kt + tx + 16 * i;        // ascending in i -> lowest-index tie win
                float ck = c[k];
                #pragma unroll
                for (int j = 0; j < 4; ++j) {
                    float t = x2r[j] + ck;               // matches reference eval order
                    float dst = t - 2.0f * acc[j][i];    // *2 exact
                    if (dst < best[j]) { best[j] = dst; bidx[j] = k; }
                }
            }
            #pragma unroll
            for (int j = 0; j < 4; ++j)
                #pragma unroll
                for (int i = 0; i < 4; ++i) acc[j][i] = 0.f;
        }

        // toggle B buffer bit (8 KB)
        #pragma unroll
        for (int i = 0; i < 4; ++i) boff[i] ^= 8192;

        __builtin_amdgcn_s_waitcnt(0);           // next-B DMA landed; this buf's reads done
        __syncthreads();
    }

    // final reduction: reuse Asl (behind the loop's last barrier)
    float* redv = Asl;                           // [64][16]
    int*   redi = (int*)(Asl + 1024);
    #pragma unroll
    for (int j = 0; j < 4; ++j) {
        int r = ty + 16 * j;
        redv[r * 16 + tx] = best[j];
        redi[r * 16 + tx] = bidx[j];
    }
    __builtin_amdgcn_s_waitcnt(0);
    __syncthreads();
    if (tid < BM) {
        float bv = redv[tid * 16]; int bi = redi[tid * 16];
        for (int t = 1; t < 16; ++t) {
            float v = redv[tid * 16 + t]; int ii = redi[tid * 16 + t];
            if (v < bv || (v == bv && ii < bi)) { bv = v; bi = ii; }  // ties -> lowest index
        }
        idx_f[row0 + tid] = (float)bi;
        atomicAdd(&counts[bi], 1u);
    }
}

// ---------------- gather: quantized_st = x + (e - x) (matches ST rounding), MSE sum ----------------
__global__ void vq_gather_kernel(const float* __restrict__ x, const float* __restrict__ emb,
                                 const float* __restrict__ idx_f, float* __restrict__ outq,
                                 double* __restrict__ sums) {
    __shared__ float red[256];
    int tid = threadIdx.x;
    int q = blockIdx.x * 256 + tid;        // float4 index, 4194304 total
    int n = q >> 6;
    int d4 = (q & 63) << 2;
    int k = (int)idx_f[n];                 // small ints stored exactly in f32
    float4 e  = *(const float4*)(emb + (size_t)k * DIM + d4);
    float4 xv = *(const float4*)(x + ((size_t)n * DIM + d4));
    float d0 = e.x - xv.x, d1 = e.y - xv.y, d2 = e.z - xv.z, d3 = e.w - xv.w;
    float4 o;
    o.x = xv.x + d0; o.y = xv.y + d1; o.z = xv.z + d2; o.w = xv.w + d3;
    *(float4*)(outq + (size_t)q * 4) = o;
    red[tid] = d0 * d0 + d1 * d1 + d2 * d2 + d3 * d3;
    __syncthreads();
    for (int off = 128; off > 0; off >>= 1) {
        if (tid < off) red[tid] += red[tid + off];
        __syncthreads();
    }
    if (tid == 0) atomicAdd(&sums[0], (double)red[0]);
}

// ---------------- sim: sum |off-diagonal cosine| ----------------
#define SPAD 68
__global__ __launch_bounds__(256)
void vq_sim_kernel(const float* __restrict__ emb, const float* __restrict__ invn,
                   double* __restrict__ sums) {
    __shared__ float Ai[64][SPAD];
    __shared__ float Bj[64][SPAD];
    int bi = blockIdx.x >> 5;
    int bj = blockIdx.x & 31;
    int tid = threadIdx.x;
    int tx = tid & 15, ty = tid >> 4;

    float acc[4][4];
    #pragma unroll
    for (int j = 0; j < 4; ++j)
        #pragma unroll
        for (int i = 0; i < 4; ++i) acc[j][i] = 0.f;

    for (int dc = 0; dc < DIM; dc += 64) {
        #pragma unroll
        for (int rr = 0; rr < 4; ++rr) {
            int row = rr * 16 + ty;
            int col = tx * 4;
            int ga = bi * 64 + row, gb = bj * 64 + row;
            float4 a = *(const float4*)(emb + (size_t)ga * DIM + dc + col);
            float4 b = *(const float4*)(emb + (size_t)gb * DIM + dc + col);
            float sa = invn[ga], sb = invn[gb];
            Ai[row][col + 0] = a.x * sa; Ai[row][col + 1] = a.y * sa;
            Ai[row][col + 2] = a.z * sa; Ai[row][col + 3] = a.w * sa;
            Bj[row][col + 0] = b.x * sb; Bj[row][col + 1] = b.y * sb;
            Bj[row][col + 2] = b.z * sb; Bj[row][col + 3] = b.w * sb;
        }
        __syncthreads();
        for (int d = 0; d < 64; d += 4) {
            float4 a[4], b[4];
            #pragma unroll
            for (int j = 0; j < 4; ++j) a[j] = *(const float4*)&Ai[ty * 4 + j][d];
            #pragma unroll
            for (int i = 0; i < 4; ++i) b[i] = *(const float4*)&Bj[tx * 4 + i][d];
            #pragma unroll
            for (int j = 0; j < 4; ++j)
                #pragma unroll
                for (int i = 0; i < 4; ++i)
                    acc[j][i] += a[j].x * b[i].x + a[j].y * b[i].y
                               + a[j].z * b[i].z + a[j].w * b[i].w;
        }
        __syncthreads();
    }
    float s = 0.f;
    #pragma unroll
    for (int j = 0; j < 4; ++j)
        #pragma unroll
        for (int i = 0; i < 4; ++i) {
            int gi = bi * 64 + ty * 4 + j;
            int gj = bj * 64 + tx * 4 + i;
            if (gi != gj) s += fabsf(acc[j][i]);
        }
    float* red = &Ai[0][0];
    red[tid] = s;
    __syncthreads();
    for (int off = 128; off > 0; off >>= 1) {
        if (tid < off) red[tid] += red[tid + off];
        __syncthreads();
    }
    if (tid == 0) atomicAdd(&sums[2], (double)red[0]);
}

// ---------------- finalize: KL, perplexity, total loss ----------------
__global__ void vq_finalize_kernel(const unsigned* __restrict__ counts,
                                   const double* __restrict__ sums,
                                   float* __restrict__ out_scalars) {
    __shared__ double sred[256];
    int tid = threadIdx.x;
    double t = 0.0;
    for (int k = tid; k < KCODES; k += 256) t += (double)counts[k];
    sred[tid] = t; __syncthreads();
    for (int off = 128; off > 0; off >>= 1) {
        if (tid < off) sred[tid] += sred[tid + off];
        __syncthreads();
    }
    double total = sred[0];
    __syncthreads();

    const double eps = 1e-8, tunif = 1.0 / (double)KCODES;
    double klsum = 0.0, plogpsum = 0.0;
    for (int k = tid; k < KCODES; k += 256) {
        double p = (double)counts[k] / total;
        klsum += (p + eps) * log((p + eps) / (tunif + eps));
        if (p > 0.0) plogpsum += p * log(p);
    }
    sred[tid] = klsum; __syncthreads();
    for (int off = 128; off > 0; off >>= 1) {
        if (tid < off) sred[tid] += sred[tid + off];
        __syncthreads();
    }
    klsum = sred[0];
    __syncthreads();
    sred[tid] = plogpsum; __syncthreads();
    for (int off = 128; off > 0; off >>= 1) {
        if (tid < off) sred[tid] += sred[tid + off];
        __syncthreads();
    }
    plogpsum = sred[0];

    if (tid == 0) {
        float mse = (float)(sums[0] / (double)((size_t)NROWS * DIM));
        float vq = mse + 0.25f * mse;                       // q_latent + COST*e_latent (equal in value)
        float kl = fminf((float)klsum, 100.0f);
        float l2 = fminf((float)(sums[1] / (double)KCODES), 10.0f);
        float orth = fminf((float)(sums[2] / ((double)KCODES * (double)KCODES)), 10.0f);
        float reg = l2 + orth;
        float total_loss = fminf(vq + 0.1f * kl + 0.01f * reg, 100.0f);
        out_scalars[0] = total_loss;
        out_scalars[1] = (float)exp(-plogpsum);
    }
}

extern "C" void kernel_launch(void* const* d_in, const int* in_sizes, int n_in,
                              void* d_out, int out_size, void* d_ws, size_t ws_size,
                              hipStream_t stream) {
    const float* x   = (const float*)d_in[0];   // (16,4096,256) f32
    const float* emb = (const float*)d_in[1];   // (2048,256)   f32
    float* out = (float*)d_out;

    char* ws = (char*)d_ws;
    float*    c      = (float*)(ws + WS_C);
    float*    invn   = (float*)(ws + WS_INV);
    unsigned* counts = (unsigned*)(ws + WS_COUNTS);
    double*   sums   = (double*)(ws + WS_SUMS);
    float*    x2g    = (float*)(ws + WS_X2);

    float* outq        = out;                 // quantized_st
    float* out_scalars = out + Q_OFF;         // loss, perplexity
    float* idx_f       = out + Q_OFF + 2;     // idx as float

    vq_init_kernel<<<1, 256, 0, stream>>>(counts, sums);
    vq_prep_kernel<<<KCODES, 64, 0, stream>>>(emb, c, invn, sums);
    vq_x2_kernel<<<NROWS / 256, 256, 0, stream>>>(x, x2g);
    vq_argmin_kernel<<<NROWS / BM, 256, 81920, stream>>>(x, emb, c, x2g, idx_f, counts);
    vq_gather_kernel<<<(NROWS * DIM / 4) / 256, 256, 0, stream>>>(x, emb, idx_f, outq, sums);
    vq_sim_kernel<<<(KCODES / 64) * (KCODES / 64), 256, 0, stream>>>(emb, invn, sums);
    vq_finalize_kernel<<<1, 256, 0, stream>>>(counts, sums, out_scalars);
}